// Round 8
// baseline (204.967 us; speedup 1.0000x reference)
//
#include <hip/hip_runtime.h>
#include <hip/hip_bf16.h>

using bf16 = __hip_bfloat16;
typedef __attribute__((ext_vector_type(8))) short bf16x8;
typedef __attribute__((ext_vector_type(4))) short bf16x4;
typedef __attribute__((ext_vector_type(4))) float f32x4;

#define HIDDEN 512
#define HEADS 8
#define HDIM 64
#define INNER 2048
#define MAXD 512
#define BB 4
#define TT 2048
#define MM (BB*TT)   /* 8192 rows */
#define LOG2E 1.44269504088896340736f

typedef const __attribute__((address_space(1))) unsigned int* gas_u32p;
typedef __attribute__((address_space(3))) unsigned int* las_u32p;

__device__ __forceinline__ void gload_lds16(const void* g, void* l) {
    __builtin_amdgcn_global_load_lds((gas_u32p)g, (las_u32p)l, 16, 0, 0);
}
__device__ __forceinline__ short bfr(float x) {
    return (short)__bfloat16_as_ushort(__float2bfloat16(x));
}

// ---------------------------------------------------------------- cast f32 -> bf16
__global__ __launch_bounds__(256) void cast_kernel(const float* __restrict__ in,
                                                   bf16* __restrict__ out) {
    int i = (blockIdx.x * 256 + threadIdx.x) * 4;
    float4 v = *(const float4*)&in[i];
    bf16 o[4] = {__float2bfloat16(v.x), __float2bfloat16(v.y),
                 __float2bfloat16(v.z), __float2bfloat16(v.w)};
    *(bf16x4*)&out[i] = *(bf16x4*)o;
}

// ---------------------------------------------------------------- weight transpose-cast: [K,N] f32 -> [N,K] bf16
__global__ __launch_bounds__(256) void wtrans_kernel(const float* __restrict__ in,
                                                     bf16* __restrict__ out,
                                                     int K, int N) {
    __shared__ float tile[32][33];
    int bx = blockIdx.x;            // N tile
    int by = blockIdx.y;            // K tile
    int lx = threadIdx.x & 31, ly = threadIdx.x >> 5;   // 32 x 8
    #pragma unroll
    for (int i = 0; i < 4; ++i)
        tile[ly + 8*i][lx] = in[(size_t)(by*32 + ly + 8*i) * N + bx*32 + lx];
    __syncthreads();
    #pragma unroll
    for (int i = 0; i < 4; ++i)
        out[(size_t)(bx*32 + ly + 8*i) * K + by*32 + lx] =
            __float2bfloat16(tile[lx][ly + 8*i]);
}

// ---------------------------------------------------------------- MFMA GEMM
// 3-deep pipeline: triple LDS buffer, counted vmcnt, raw s_barrier.
// C[M,N] = A[M,K] @ BT[N,K]^T + bias
// EPI: 0=bf16 out, 1=f32 out (+resid if RESID), 2=tanh-gelu->bf16
// VT: qkv mode — blocks with n0>=1024 write transposed V into vt_out instead of C
template<int EPI, int BN, int VT, int RESID>
__global__ __launch_bounds__(256) void gemm_kernel(
    const bf16* __restrict__ A, const bf16* __restrict__ BT,
    const float* __restrict__ bias, const float* __restrict__ resid,
    void* __restrict__ C, bf16* __restrict__ vt_out,
    int M, int N, int K)
{
    constexpr int NBF = BN / 32;              // B-frags per wave (4 or 2)
    constexpr int BBYTES = BN * 64;           // bytes per B buffer (BN x 32 x 2B)
    __shared__ __align__(16) bf16 As[3*128*32];
    __shared__ __align__(16) bf16 Bs[3*BN*32];
    const int tid = threadIdx.x;
    const int wid = tid >> 6;
    const int lane = tid & 63;
    const int lhi = lane >> 4, llo = lane & 15;
    const int m0 = blockIdx.x * 128, n0 = blockIdx.y * BN;
    const int wr = wid >> 1, wc = wid & 1;

    const int srow = tid >> 2, scol = (tid & 3) * 8; // 16B per thread, rows 0-63
    const bf16* Ap = A + (size_t)(m0 + srow) * K + scol;
    const bf16* Bp = BT + (size_t)(n0 + srow) * K + scol;
    const size_t step64 = (size_t)64 * K;

    f32x4 acc[4][NBF] = {};

    // stage tile t into buffer bi
    auto STAGE = [&](int t, int bi) {
        const int k = t << 5;
        gload_lds16(Ap + k,          (char*)As + bi*8192 + tid*16);
        gload_lds16(Ap + k + step64, (char*)As + bi*8192 + 4096 + tid*16);
        gload_lds16(Bp + k,          (char*)Bs + bi*BBYTES + tid*16);
        if (BN == 128) gload_lds16(Bp + k + step64, (char*)Bs + bi*BBYTES + 4096 + tid*16);
    };

    const int NK = K >> 5;
    STAGE(0, 0);
    STAGE(1, 1);
    if constexpr (BN == 128) asm volatile("s_waitcnt vmcnt(4)" ::: "memory");
    else                     asm volatile("s_waitcnt vmcnt(3)" ::: "memory");
    __builtin_amdgcn_s_barrier();
    __builtin_amdgcn_sched_barrier(0);

    int p = 0;
    for (int it = 0; it < NK; ++it) {
        const int pn2 = (p == 0) ? 2 : p - 1;        // (p+2)%3
        if (it + 2 < NK) STAGE(it + 2, pn2);
        bf16x8 af[4], bfrg[NBF];
        #pragma unroll
        for (int ar = 0; ar < 4; ++ar)
            af[ar] = *(const bf16x8*)((const char*)As + p*8192 + (64*wr + 16*ar + llo)*64 + lhi*16);
        #pragma unroll
        for (int bc = 0; bc < NBF; ++bc)
            bfrg[bc] = *(const bf16x8*)((const char*)Bs + p*BBYTES + ((BN/2)*wc + 16*bc + llo)*64 + lhi*16);
        #pragma unroll
        for (int ar = 0; ar < 4; ++ar)
            #pragma unroll
            for (int bc = 0; bc < NBF; ++bc)
                acc[ar][bc] = __builtin_amdgcn_mfma_f32_16x16x32_bf16(
                    af[ar], bfrg[bc], acc[ar][bc], 0, 0, 0);
        if constexpr (BN == 128) asm volatile("s_waitcnt vmcnt(4)" ::: "memory");
        else                     asm volatile("s_waitcnt vmcnt(3)" ::: "memory");
        __builtin_amdgcn_s_barrier();
        __builtin_amdgcn_sched_barrier(0);
        p = (p == 2) ? 0 : p + 1;
    }

    if (VT && n0 >= 1024) {
        // V block of qkv: write only transposed v_t[bh][d][t], packed 4 t per store
        #pragma unroll
        for (int ar = 0; ar < 4; ++ar) {
            const int row = m0 + 64*wr + 16*ar + 4*lhi;   // +j
            const int bq = row >> 11, t0 = row & 2047;
            #pragma unroll
            for (int bc = 0; bc < NBF; ++bc) {
                const int cv = n0 - 1024 + (BN/2)*wc + 16*bc + llo;
                const int h = cv >> 6, d = cv & 63;
                float bv = bias[n0 + (BN/2)*wc + 16*bc + llo];
                bf16x4 pk = {bfr(acc[ar][bc][0] + bv), bfr(acc[ar][bc][1] + bv),
                             bfr(acc[ar][bc][2] + bv), bfr(acc[ar][bc][3] + bv)};
                *(bf16x4*)&vt_out[(((size_t)(bq*8 + h) * 64 + d) << 11) + t0] = pk;
            }
        }
        return;
    }

    #pragma unroll
    for (int ar = 0; ar < 4; ++ar) {
        #pragma unroll
        for (int j = 0; j < 4; ++j) {
            int row = m0 + 64*wr + 16*ar + 4*lhi + j;
            #pragma unroll
            for (int bc = 0; bc < NBF; ++bc) {
                int col = n0 + (BN/2)*wc + 16*bc + llo;
                float v = acc[ar][bc][j] + bias[col];
                if (RESID) v += resid[(size_t)row * N + col];
                if (EPI == 2) {
                    float u = 0.7978845608028654f * (v + 0.044715f * v * v * v);
                    float e = __builtin_amdgcn_exp2f(u * (2.0f * LOG2E));
                    v = v * (1.0f - 1.0f / (1.0f + e));   // 0.5v(1+tanh(u))
                }
                if (EPI == 1)
                    ((float*)C)[(size_t)row * N + col] = v;
                else
                    ((bf16*)C)[(size_t)row * N + col] = __float2bfloat16(v);
            }
        }
    }
}

// ---------------------------------------------------------------- flash attention
// 4 waves x 32 q-cols each (QBLK=128): every K/V ds_read_b128 feeds TWO MFMAs
// (two q-half B-frags) -> LDS-issue traffic per q halves vs 16q/wave.
// Swapped QK^T, fixed-max softmax, padded bias table, 3-deep K/V pipeline.
#define PTN (TT + 128)
__global__ __launch_bounds__(256) void attn_kernel(
    const bf16* __restrict__ qkv,    // [B*T, 1536]
    const bf16* __restrict__ v_t,    // [B*H, 64, T]
    const float* __restrict__ rel_table,   // [1025, 8]
    bf16* __restrict__ attn_out)     // [B*T, 512]
{
    __shared__ __align__(16) bf16 Ks[3*64*64];    // [kv][d], swizzled
    __shared__ __align__(16) bf16 Vs[3*64*64];    // [d][kv], swizzled
    __shared__ __align__(16) bf16 Ps[4*32*64];    // per-wave [32 q][kv], swizzled
    __shared__ float PT[PTN];                     // bias*LOG2E, pre-clamped

    const int qt = blockIdx.x, bh = blockIdx.y;
    const int b = bh >> 3, h = bh & 7;
    const int tid = threadIdx.x, wid = tid >> 6, lane = tid & 63;
    const int lhi = lane >> 4, llo = lane & 15;

    // padded bias table: PT[i] = bias(d = i + lo), lo = qt*128 - (TT-1)
    const int lo = qt * 128 - (TT - 1);
    for (int i = tid; i < PTN; i += 256) {
        int idx = min(max(i + lo, -MAXD), MAXD) + MAXD;
        PT[i] = rel_table[(size_t)idx * HEADS + h] * LOG2E;
    }

    const int q0w = qt * 128 + wid * 32;
    bf16x8 bq[2][2];
    #pragma unroll
    for (int qh = 0; qh < 2; ++qh)
        #pragma unroll
        for (int kc = 0; kc < 2; ++kc)
            bq[qh][kc] = *(const bf16x8*)&qkv[(size_t)(b*TT + q0w + 16*qh + llo) * 1536
                                              + h*64 + kc*32 + lhi*8];

    // staging coords: 256 thr x 16B = 4KB per call; 2 calls per 8KB tile
    const int so = tid * 16;
    const int r0 = so >> 7;                                   // 0..31
    const int c0 = (((so & 127) ^ ((r0 & 7) << 4)) >> 1);     // source element col
    const bf16* kbase = qkv + (size_t)(b*TT) * 1536 + 512 + h*64;
    const bf16* vbase = v_t + (size_t)bh * 64 * TT;

    float accL[2] = {};
    f32x4 accO[2][4] = {};

    auto STAGE = [&](int t, int bi) {
        const int kv = t * 64;
        gload_lds16(kbase + (size_t)(kv + r0) * 1536 + c0,      (char*)Ks + bi*8192 + so);
        gload_lds16(kbase + (size_t)(kv + r0 + 32) * 1536 + c0, (char*)Ks + bi*8192 + so + 4096);
        gload_lds16(vbase + (size_t)r0 * TT + kv + c0,          (char*)Vs + bi*8192 + so);
        gload_lds16(vbase + (size_t)(r0 + 32) * TT + kv + c0,   (char*)Vs + bi*8192 + so + 4096);
    };

    constexpr int NT = TT / 64;
    STAGE(0, 0);
    STAGE(1, 1);
    asm volatile("s_waitcnt vmcnt(4) lgkmcnt(0)" ::: "memory");   // tile0 + PT ready
    __builtin_amdgcn_s_barrier();
    __builtin_amdgcn_sched_barrier(0);

    int p = 0;
    for (int kt = 0; kt < NT; ++kt) {
        const int kv0 = kt * 64;
        const int pn2 = (p == 0) ? 2 : p - 1;        // (p+2)%3
        if (kt + 2 < NT) STAGE(kt + 2, pn2);
        const char* Kb = (const char*)Ks + p*8192;
        const char* Vb = (const char*)Vs + p*8192;

        // S^T[kv][q] = mfma(A=K, B=Q); each K-frag feeds both q-halves
        f32x4 s[2][4] = {};
        __builtin_amdgcn_s_setprio(1);
        #pragma unroll
        for (int f = 0; f < 4; ++f) {
            const int rr = 16*f + llo;
            #pragma unroll
            for (int kc = 0; kc < 2; ++kc) {
                bf16x8 ak = *(const bf16x8*)(Kb + rr*128 + (((4*kc + lhi) ^ (rr & 7)) << 4));
                #pragma unroll
                for (int qh = 0; qh < 2; ++qh)
                    s[qh][f] = __builtin_amdgcn_mfma_f32_16x16x32_bf16(
                        ak, bq[qh][kc], s[qh][f], 0, 0, 0);
            }
        }
        __builtin_amdgcn_s_setprio(0);

        // bias (exp2 domain, clamp-free) + exp2 + sum + pack P
        #pragma unroll
        for (int qh = 0; qh < 2; ++qh) {
            const int ibq = wid*32 + 16*qh + llo + (TT - 1) - kv0 - 4*lhi;
            #pragma unroll
            for (int f = 0; f < 4; ++f)
                #pragma unroll
                for (int j = 0; j < 4; ++j)
                    s[qh][f][j] = s[qh][f][j] * (0.125f * LOG2E) + PT[ibq - 16*f - j];
            float tf[4];
            const int prow = qt ? 0 : 0;   // (no-op; keep indices simple)
            #pragma unroll
            for (int f = 0; f < 4; ++f) {
                float p0 = __builtin_amdgcn_exp2f(s[qh][f][0]);
                float p1 = __builtin_amdgcn_exp2f(s[qh][f][1]);
                float p2 = __builtin_amdgcn_exp2f(s[qh][f][2]);
                float p3 = __builtin_amdgcn_exp2f(s[qh][f][3]);
                tf[f] = (p0 + p1) + (p2 + p3);
                bf16x4 pk = {bfr(p0), bfr(p1), bfr(p2), bfr(p3)};
                *(bf16x4*)((char*)Ps + wid*4096 + (16*qh + llo)*128 +
                           ((f*32 + lhi*8) ^ ((llo & 7) << 4))) = pk;
            }
            accL[qh] += (tf[0] + tf[1]) + (tf[2] + tf[3]);
        }

        // O^T[d][q] += mfma(A=V^T, B=P^T); each V-frag feeds both q-halves
        bf16x8 pf[2][2];
        #pragma unroll
        for (int qh = 0; qh < 2; ++qh)
            #pragma unroll
            for (int kc = 0; kc < 2; ++kc)
                pf[qh][kc] = *(const bf16x8*)((const char*)Ps + wid*4096 + (16*qh + llo)*128 +
                                              ((kc*64 + lhi*16) ^ ((llo & 7) << 4)));
        __builtin_amdgcn_s_setprio(1);
        #pragma unroll
        for (int f = 0; f < 4; ++f) {
            const int rr = 16*f + llo;
            #pragma unroll
            for (int kc = 0; kc < 2; ++kc) {
                bf16x8 av = *(const bf16x8*)(Vb + rr*128 + (((4*kc + lhi) ^ (rr & 7)) << 4));
                #pragma unroll
                for (int qh = 0; qh < 2; ++qh)
                    accO[qh][f] = __builtin_amdgcn_mfma_f32_16x16x32_bf16(
                        av, pf[qh][kc], accO[qh][f], 0, 0, 0);
            }
        }
        __builtin_amdgcn_s_setprio(0);

        asm volatile("s_waitcnt vmcnt(4)" ::: "memory");
        __builtin_amdgcn_s_barrier();
        __builtin_amdgcn_sched_barrier(0);
        p = (p == 2) ? 0 : p + 1;
    }

    // deferred l reduce across lhi groups (kv quarters); write O
    #pragma unroll
    for (int qh = 0; qh < 2; ++qh) {
        float l = accL[qh];
        l += __shfl_xor(l, 16, 64);
        l += __shfl_xor(l, 32, 64);
        const float rl = 1.0f / l;
        const int row = b*TT + q0w + 16*qh + llo;
        #pragma unroll
        for (int f = 0; f < 4; ++f) {
            bf16x4 ov = {bfr(accO[qh][f][0] * rl), bfr(accO[qh][f][1] * rl),
                         bfr(accO[qh][f][2] * rl), bfr(accO[qh][f][3] * rl)};
            *(bf16x4*)&attn_out[(size_t)row * HIDDEN + h*64 + 16*f + 4*lhi] = ov;
        }
    }
}

// ---------------------------------------------------------------- LayerNorm (input already has residual added)
template<int WB>
__global__ __launch_bounds__(256) void ln_kernel(
    const float* __restrict__ in,
    const float* __restrict__ g, const float* __restrict__ bb,
    float* __restrict__ of, bf16* __restrict__ ob)
{
    int row = blockIdx.x * 4 + (threadIdx.x >> 6);
    int lane = threadIdx.x & 63;
    const float* pa = in + (size_t)row * HIDDEN;
    float v[8];
    float s = 0.f, sq = 0.f;
    #pragma unroll
    for (int i = 0; i < 2; ++i) {
        float4 a4 = *(const float4*)&pa[lane*4 + i*256];
        v[i*4+0] = a4.x; v[i*4+1] = a4.y; v[i*4+2] = a4.z; v[i*4+3] = a4.w;
        #pragma unroll
        for (int j = 0; j < 4; ++j) { s += v[i*4+j]; sq += v[i*4+j]*v[i*4+j]; }
    }
    #pragma unroll
    for (int d = 1; d < 64; d <<= 1) {
        s  += __shfl_xor(s,  d, 64);
        sq += __shfl_xor(sq, d, 64);
    }
    float mean = s * (1.f / HIDDEN);
    float var  = sq * (1.f / HIDDEN) - mean * mean;
    float rstd = rsqrtf(var + 1e-5f);
    #pragma unroll
    for (int i = 0; i < 2; ++i)
        #pragma unroll
        for (int j = 0; j < 4; ++j) {
            int col = lane*4 + i*256 + j;
            float o = (v[i*4+j] - mean) * rstd * g[col] + bb[col];
            of[(size_t)row * HIDDEN + col] = o;
            if (WB) ob[(size_t)row * HIDDEN + col] = __float2bfloat16(o);
        }
}

// ---------------------------------------------------------------- launcher
extern "C" void kernel_launch(void* const* d_in, const int* in_sizes, int n_in,
                              void* d_out, int out_size, void* d_ws, size_t ws_size,
                              hipStream_t stream) {
    const float* x     = (const float*)d_in[0];
    const float* w_qkv = (const float*)d_in[1];
    const float* b_qkv = (const float*)d_in[2];
    const float* w_out = (const float*)d_in[3];
    const float* b_out = (const float*)d_in[4];
    const float* ln1_g = (const float*)d_in[5];
    const float* ln1_b = (const float*)d_in[6];
    const float* ln2_g = (const float*)d_in[7];
    const float* ln2_b = (const float*)d_in[8];
    const float* w1    = (const float*)d_in[9];
    const float* b1    = (const float*)d_in[10];
    const float* w2    = (const float*)d_in[11];
    const float* b2    = (const float*)d_in[12];
    const float* rel   = (const float*)d_in[13];
    float* out = (float*)d_out;

    char* ws = (char*)d_ws;
    bf16*  xb     = (bf16*)(ws + 0);
    bf16*  wqkv_t = (bf16*)(ws + 8388608);
    bf16*  wout_t = (bf16*)(ws + 9961472);
    bf16*  w1_t   = (bf16*)(ws + 10485760);
    bf16*  w2_t   = (bf16*)(ws + 12582912);
    bf16*  qkv    = (bf16*)(ws + 14680064);
    bf16*  v_t    = (bf16*)(ws + 39845888);
    bf16*  attn_o = (bf16*)(ws + 48234496);
    float* proj   = (float*)(ws + 56623104);
    float* x1     = (float*)(ws + 73400320);
    bf16*  h      = (bf16*)(ws + 14680064);   // reuses qkv+v_t (dead after attention)
    bf16*  x1b    = (bf16*)(ws + 90177536);

    // 1. casts / weight transposes
    cast_kernel<<<MM*HIDDEN/4/256, 256, 0, stream>>>(x, xb);
    wtrans_kernel<<<dim3(1536/32, 512/32),  256, 0, stream>>>(w_qkv, wqkv_t, 512, 1536);
    wtrans_kernel<<<dim3(512/32,  512/32),  256, 0, stream>>>(w_out, wout_t, 512, 512);
    wtrans_kernel<<<dim3(2048/32, 512/32),  256, 0, stream>>>(w1,    w1_t,   512, 2048);
    wtrans_kernel<<<dim3(512/32,  2048/32), 256, 0, stream>>>(w2,    w2_t,   2048, 512);
    // 2. qkv projection (V blocks write v_t directly)
    gemm_kernel<0,128,1,0><<<dim3(MM/128, 1536/128), 256, 0, stream>>>(
        xb, wqkv_t, b_qkv, nullptr, qkv, v_t, MM, 1536, 512);
    // 3. flash attention (128 q-rows per block, 4 waves x 32q)
    attn_kernel<<<dim3(TT/128, BB*HEADS), 256, 0, stream>>>(qkv, v_t, rel, attn_o);
    // 4. output projection + residual(x) -> f32
    gemm_kernel<1,64,0,1><<<dim3(MM/128, 512/64), 256, 0, stream>>>(
        attn_o, wout_t, b_out, x, proj, nullptr, MM, 512, 512);
    // 5. LN1
    ln_kernel<1><<<MM/4, 256, 0, stream>>>(proj, ln1_g, ln1_b, x1, x1b);
    // 6. MLP up + GELU(tanh)
    gemm_kernel<2,128,0,0><<<dim3(MM/128, 2048/128), 256, 0, stream>>>(
        x1b, w1_t, b1, nullptr, h, nullptr, MM, 2048, 512);
    // 7. MLP down + residual(x1) -> f32
    gemm_kernel<1,64,0,1><<<dim3(MM/128, 512/64), 256, 0, stream>>>(
        h, w2_t, b2, x1, proj, nullptr, MM, 512, 2048);
    // 8. LN2 -> output
    ln_kernel<0><<<MM/4, 256, 0, stream>>>(proj, ln2_g, ln2_b, out, nullptr);
}

// Round 9
// 191.791 us; speedup vs baseline: 1.0687x; 1.0687x over previous
//
#include <hip/hip_runtime.h>
#include <hip/hip_bf16.h>

using bf16 = __hip_bfloat16;
typedef __attribute__((ext_vector_type(8))) short bf16x8;
typedef __attribute__((ext_vector_type(4))) short bf16x4;
typedef __attribute__((ext_vector_type(4))) float f32x4;

#define HIDDEN 512
#define HEADS 8
#define HDIM 64
#define INNER 2048
#define MAXD 512
#define BB 4
#define TT 2048
#define MM (BB*TT)   /* 8192 rows */
#define LOG2E 1.44269504088896340736f

typedef const __attribute__((address_space(1))) unsigned int* gas_u32p;
typedef __attribute__((address_space(3))) unsigned int* las_u32p;

__device__ __forceinline__ void gload_lds16(const void* g, void* l) {
    __builtin_amdgcn_global_load_lds((gas_u32p)g, (las_u32p)l, 16, 0, 0);
}
__device__ __forceinline__ short bfr(float x) {
    return (short)__bfloat16_as_ushort(__float2bfloat16(x));
}

// ---------------------------------------------------------------- cast f32 -> bf16
__global__ __launch_bounds__(256) void cast_kernel(const float* __restrict__ in,
                                                   bf16* __restrict__ out) {
    int i = (blockIdx.x * 256 + threadIdx.x) * 4;
    float4 v = *(const float4*)&in[i];
    bf16 o[4] = {__float2bfloat16(v.x), __float2bfloat16(v.y),
                 __float2bfloat16(v.z), __float2bfloat16(v.w)};
    *(bf16x4*)&out[i] = *(bf16x4*)o;
}

// ---------------------------------------------------------------- weight transpose-cast: [K,N] f32 -> [N,K] bf16
__global__ __launch_bounds__(256) void wtrans_kernel(const float* __restrict__ in,
                                                     bf16* __restrict__ out,
                                                     int K, int N) {
    __shared__ float tile[32][33];
    int bx = blockIdx.x;            // N tile
    int by = blockIdx.y;            // K tile
    int lx = threadIdx.x & 31, ly = threadIdx.x >> 5;   // 32 x 8
    #pragma unroll
    for (int i = 0; i < 4; ++i)
        tile[ly + 8*i][lx] = in[(size_t)(by*32 + ly + 8*i) * N + bx*32 + lx];
    __syncthreads();
    #pragma unroll
    for (int i = 0; i < 4; ++i)
        out[(size_t)(bx*32 + ly + 8*i) * K + by*32 + lx] =
            __float2bfloat16(tile[lx][ly + 8*i]);
}

// ---------------------------------------------------------------- MFMA GEMM, 2-phase prefetch double-buffer
// LDS rows 64B with 16B-granule XOR swizzle (g ^= (row>>1)&3): fragment reads
// 8-way -> 2-way bank conflict. Inverse swizzle folded into staging SOURCE
// address (gload_lds dest stays linear, rule #21).
// C[M,N] = A[M,K] @ BT[N,K]^T + bias
// EPI: 0=bf16 out, 1=f32 out (+resid if RESID), 2=tanh-gelu->bf16
// VT: qkv mode — blocks with n0>=1024 write transposed V into vt_out instead of C
template<int EPI, int BN, int VT, int RESID>
__global__ __launch_bounds__(256) void gemm_kernel(
    const bf16* __restrict__ A, const bf16* __restrict__ BT,
    const float* __restrict__ bias, const float* __restrict__ resid,
    void* __restrict__ C, bf16* __restrict__ vt_out,
    int M, int N, int K)
{
    constexpr int NBF = BN / 32;              // B-frags per wave (4 or 2)
    constexpr int BBYTES = BN * 64;           // bytes per B buffer (BN x 32 x 2B)
    __shared__ __align__(16) bf16 As[2][128*32];
    __shared__ __align__(16) bf16 Bs[2][BN*32];
    const int tid = threadIdx.x;
    const int wid = tid >> 6;
    const int lane = tid & 63;
    const int lhi = lane >> 4, llo = lane & 15;
    const int m0 = blockIdx.x * 128, n0 = blockIdx.y * BN;
    const int wr = wid >> 1, wc = wid & 1;

    // staging: thread tid fills LDS bytes [tid*16, +16) = row (tid>>2), granule (tid&3);
    // source column chunk is inverse-swizzled so swizzled reads see correct data
    const int srow = tid >> 2;
    const int scol = ((tid & 3) ^ ((srow >> 1) & 3)) * 8;
    const bf16* Ap = A + (size_t)(m0 + srow) * K + scol;
    const bf16* Bp = BT + (size_t)(n0 + srow) * K + scol;
    const size_t step64 = (size_t)64 * K;
    const int rsw = (llo >> 1) & 3;           // read-side swizzle (row>>1)&3

    f32x4 acc[4][NBF] = {};

    // prologue stage k=0 into buffer 0
    gload_lds16(Ap,          (char*)As + tid*16);
    gload_lds16(Ap + step64, (char*)As + 4096 + tid*16);
    gload_lds16(Bp,          (char*)Bs + tid*16);
    if (BN == 128) gload_lds16(Bp + step64, (char*)Bs + 4096 + tid*16);

    const int NK = K >> 5;
    for (int it = 0; it < NK; ++it) {
        const int p = it & 1;
        __syncthreads();                       // drains vmcnt -> buf p ready
        if (it + 1 < NK) {                     // prefetch next tile into buf p^1
            const int k1 = (it + 1) << 5;
            gload_lds16(Ap + k1,          (char*)As + (p^1)*8192 + tid*16);
            gload_lds16(Ap + k1 + step64, (char*)As + (p^1)*8192 + 4096 + tid*16);
            gload_lds16(Bp + k1,          (char*)Bs + (p^1)*BBYTES + tid*16);
            if (BN == 128) gload_lds16(Bp + k1 + step64, (char*)Bs + (p^1)*BBYTES + 4096 + tid*16);
        }
        bf16x8 af[4], bfrg[NBF];
        #pragma unroll
        for (int ar = 0; ar < 4; ++ar)
            af[ar] = *(const bf16x8*)((const char*)As + p*8192 +
                       (64*wr + 16*ar + llo)*64 + ((lhi ^ rsw) << 4));
        #pragma unroll
        for (int bc = 0; bc < NBF; ++bc)
            bfrg[bc] = *(const bf16x8*)((const char*)Bs + p*BBYTES +
                       ((BN/2)*wc + 16*bc + llo)*64 + ((lhi ^ rsw) << 4));
        #pragma unroll
        for (int ar = 0; ar < 4; ++ar)
            #pragma unroll
            for (int bc = 0; bc < NBF; ++bc)
                acc[ar][bc] = __builtin_amdgcn_mfma_f32_16x16x32_bf16(
                    af[ar], bfrg[bc], acc[ar][bc], 0, 0, 0);
    }

    if (VT && n0 >= 1024) {
        // V block of qkv: write only transposed v_t[bh][d][t], packed 4 t per store
        #pragma unroll
        for (int ar = 0; ar < 4; ++ar) {
            const int row = m0 + 64*wr + 16*ar + 4*lhi;   // +j
            const int bq = row >> 11, t0 = row & 2047;
            #pragma unroll
            for (int bc = 0; bc < NBF; ++bc) {
                const int cv = n0 - 1024 + (BN/2)*wc + 16*bc + llo;
                const int h = cv >> 6, d = cv & 63;
                float bv = bias[n0 + (BN/2)*wc + 16*bc + llo];
                bf16x4 pk = {bfr(acc[ar][bc][0] + bv), bfr(acc[ar][bc][1] + bv),
                             bfr(acc[ar][bc][2] + bv), bfr(acc[ar][bc][3] + bv)};
                *(bf16x4*)&vt_out[(((size_t)(bq*8 + h) * 64 + d) << 11) + t0] = pk;
            }
        }
        return;
    }

    #pragma unroll
    for (int ar = 0; ar < 4; ++ar) {
        #pragma unroll
        for (int j = 0; j < 4; ++j) {
            int row = m0 + 64*wr + 16*ar + 4*lhi + j;
            #pragma unroll
            for (int bc = 0; bc < NBF; ++bc) {
                int col = n0 + (BN/2)*wc + 16*bc + llo;
                float v = acc[ar][bc][j] + bias[col];
                if (RESID) v += resid[(size_t)row * N + col];
                if (EPI == 2) {
                    float u = 0.7978845608028654f * (v + 0.044715f * v * v * v);
                    float e = __builtin_amdgcn_exp2f(u * (2.0f * LOG2E));
                    v = v * (1.0f - 1.0f / (1.0f + e));   // 0.5v(1+tanh(u))
                }
                if (EPI == 1)
                    ((float*)C)[(size_t)row * N + col] = v;
                else
                    ((bf16*)C)[(size_t)row * N + col] = __float2bfloat16(v);
            }
        }
    }
}

// ---------------------------------------------------------------- flash attention
// Round-5 structure (proven 60.5 us): swapped QK^T, fixed-max softmax, padded
// bias table, QBLK=128 / 8 waves x 16q, 2-phase K/V prefetch.
// NEW: wave-uniform far-tile branch skips the 16 PT ds_read_b32 on fully
// clamped tiles (~40% of tiles) using register constants.
#define PTN (TT + 128)
__global__ __launch_bounds__(512) void attn_kernel(
    const bf16* __restrict__ qkv,    // [B*T, 1536]
    const bf16* __restrict__ v_t,    // [B*H, 64, T]
    const float* __restrict__ rel_table,   // [1025, 8]
    bf16* __restrict__ attn_out)     // [B*T, 512]
{
    __shared__ __align__(16) bf16 Ks[2][64*64];   // [kv][d], swizzled
    __shared__ __align__(16) bf16 Vs[2][64*64];   // [d][kv], swizzled
    __shared__ __align__(16) bf16 Ps[8][16*64];   // per-wave [q][kv], swizzled
    __shared__ float PT[PTN];                     // bias*LOG2E, pre-clamped

    const int qt = blockIdx.x, bh = blockIdx.y;
    const int b = bh >> 3, h = bh & 7;
    const int tid = threadIdx.x, wid = tid >> 6, lane = tid & 63;
    const int lhi = lane >> 4, llo = lane & 15;

    // padded bias table: PT[i] = bias(d = i + lo), lo = qt*128 - (TT-1)
    const int lo = qt * 128 - (TT - 1);
    for (int i = tid; i < PTN; i += 512) {
        int idx = min(max(i + lo, -MAXD), MAXD) + MAXD;
        PT[i] = rel_table[(size_t)idx * HEADS + h] * LOG2E;
    }

    const int q0w = qt * 128 + wid * 16;
    const int qb = qt * 128;                 // block q base
    const int q = q0w + llo;                 // this lane's q column
    bf16x8 bq[2];
    #pragma unroll
    for (int kc = 0; kc < 2; ++kc)
        bq[kc] = *(const bf16x8*)&qkv[(size_t)(b*TT + q) * 1536 + h*64 + kc*32 + lhi*8];

    // staging coords: 512 thr x 16B = one 8KB tile each for K and V
    const int so = tid * 16;
    const int r0 = so >> 7;                                   // 0..63
    const int c0 = (((so & 127) ^ ((r0 & 7) << 4)) >> 1);     // source element col
    const bf16* kbase = qkv + (size_t)(b*TT) * 1536 + 512 + h*64;
    const bf16* vbase = v_t + (size_t)bh * 64 * TT;

    float accL = 0.f;
    f32x4 accO[4] = {};
    const int pti = wid*16 + llo + (TT - 1);   // PT index base (before -kv0)

    // prologue: stage tile 0 into buffer 0
    gload_lds16(kbase + (size_t)r0 * 1536 + c0, (char*)Ks + so);
    gload_lds16(vbase + (size_t)r0 * TT + c0,   (char*)Vs + so);
    __syncthreads();   // PT + tile0 ready (vmcnt+lgkm drain)

    // far-clamp constants (guarded reads; unused when invalid)
    const float cFut  = PT[min(max(-512 - lo, 0), PTN - 1)];   // q-kv <= -512
    const float cPast = PT[min(max( 512 - lo, 0), PTN - 1)];   // q-kv >=  512

    constexpr int NT = TT / 64;
    for (int kt = 0; kt < NT; ++kt) {
        const int p = kt & 1;
        const int kv0 = kt * 64;
        if (kt) __syncthreads();            // buf p staged
        if (kt + 1 < NT) {                  // prefetch next kv tile
            const int kn = kv0 + 64;
            gload_lds16(kbase + (size_t)(kn + r0) * 1536 + c0, (char*)Ks + (p^1)*8192 + so);
            gload_lds16(vbase + (size_t)r0 * TT + kn + c0,     (char*)Vs + (p^1)*8192 + so);
        }
        const char* Kb = (const char*)Ks + p*8192;
        const char* Vb = (const char*)Vs + p*8192;

        // S^T[kv][q] = mfma(A=K, B=Q)
        f32x4 s[4];
        __builtin_amdgcn_s_setprio(1);
        #pragma unroll
        for (int f = 0; f < 4; ++f) {
            f32x4 a = {};
            const int rr = 16*f + llo;
            #pragma unroll
            for (int kc = 0; kc < 2; ++kc) {
                bf16x8 ak = *(const bf16x8*)(Kb + rr*128 + (((4*kc + lhi) ^ (rr & 7)) << 4));
                a = __builtin_amdgcn_mfma_f32_16x16x32_bf16(ak, bq[kc], a, 0, 0, 0);
            }
            s[f] = a;
        }
        __builtin_amdgcn_s_setprio(0);

        // bias (exp2 domain): far tiles use register constant (no LDS reads)
        const float sc = 0.125f * LOG2E;
        if (kv0 >= qb + 640) {                       // whole tile q-kv <= -512
            #pragma unroll
            for (int f = 0; f < 4; ++f)
                #pragma unroll
                for (int j = 0; j < 4; ++j)
                    s[f][j] = fmaf(s[f][j], sc, cFut);
        } else if (kv0 + 576 <= qb) {                // whole tile q-kv >= 512
            #pragma unroll
            for (int f = 0; f < 4; ++f)
                #pragma unroll
                for (int j = 0; j < 4; ++j)
                    s[f][j] = fmaf(s[f][j], sc, cPast);
        } else {                                     // padded table, clamp-free
            const int ib = pti - kv0;
            #pragma unroll
            for (int f = 0; f < 4; ++f)
                #pragma unroll
                for (int j = 0; j < 4; ++j)
                    s[f][j] = fmaf(s[f][j], sc, PT[ib - 16*f - 4*lhi - j]);
        }

        // exp2 + sum + pack P (kv-contiguous j -> bf16x4 -> ds_write_b64)
        float tf[4];
        #pragma unroll
        for (int f = 0; f < 4; ++f) {
            float p0 = __builtin_amdgcn_exp2f(s[f][0]);
            float p1 = __builtin_amdgcn_exp2f(s[f][1]);
            float p2 = __builtin_amdgcn_exp2f(s[f][2]);
            float p3 = __builtin_amdgcn_exp2f(s[f][3]);
            tf[f] = (p0 + p1) + (p2 + p3);
            bf16x4 pk = {bfr(p0), bfr(p1), bfr(p2), bfr(p3)};
            *(bf16x4*)((char*)Ps + wid*2048 + llo*128 +
                       ((f*32 + lhi*8) ^ ((llo & 7) << 4))) = pk;
        }
        accL += (tf[0] + tf[1]) + (tf[2] + tf[3]);

        // O^T[d][q] += mfma(A=V^T, B=P^T)
        bf16x8 pf[2];
        #pragma unroll
        for (int kc = 0; kc < 2; ++kc)
            pf[kc] = *(const bf16x8*)((const char*)Ps + wid*2048 + llo*128 +
                                      ((kc*64 + lhi*16) ^ ((llo & 7) << 4)));
        __builtin_amdgcn_s_setprio(1);
        #pragma unroll
        for (int kc = 0; kc < 2; ++kc)
            #pragma unroll
            for (int f = 0; f < 4; ++f) {
                const int rr = 16*f + llo;
                bf16x8 av = *(const bf16x8*)(Vb + rr*128 + (((4*kc + lhi) ^ (rr & 7)) << 4));
                accO[f] = __builtin_amdgcn_mfma_f32_16x16x32_bf16(av, pf[kc], accO[f], 0, 0, 0);
            }
        __builtin_amdgcn_s_setprio(0);
    }

    // deferred l reduce across lhi groups (kv quarters)
    accL += __shfl_xor(accL, 16, 64);
    accL += __shfl_xor(accL, 32, 64);
    const float rl = 1.0f / accL;
    const int row = b*TT + q;
    #pragma unroll
    for (int f = 0; f < 4; ++f) {
        bf16x4 ov = {bfr(accO[f][0] * rl), bfr(accO[f][1] * rl),
                     bfr(accO[f][2] * rl), bfr(accO[f][3] * rl)};
        *(bf16x4*)&attn_out[(size_t)row * HIDDEN + h*64 + 16*f + 4*lhi] = ov;
    }
}

// ---------------------------------------------------------------- LayerNorm (input already has residual added)
template<int WB>
__global__ __launch_bounds__(256) void ln_kernel(
    const float* __restrict__ in,
    const float* __restrict__ g, const float* __restrict__ bb,
    float* __restrict__ of, bf16* __restrict__ ob)
{
    int row = blockIdx.x * 4 + (threadIdx.x >> 6);
    int lane = threadIdx.x & 63;
    const float* pa = in + (size_t)row * HIDDEN;
    float v[8];
    float s = 0.f, sq = 0.f;
    #pragma unroll
    for (int i = 0; i < 2; ++i) {
        float4 a4 = *(const float4*)&pa[lane*4 + i*256];
        v[i*4+0] = a4.x; v[i*4+1] = a4.y; v[i*4+2] = a4.z; v[i*4+3] = a4.w;
        #pragma unroll
        for (int j = 0; j < 4; ++j) { s += v[i*4+j]; sq += v[i*4+j]*v[i*4+j]; }
    }
    #pragma unroll
    for (int d = 1; d < 64; d <<= 1) {
        s  += __shfl_xor(s,  d, 64);
        sq += __shfl_xor(sq, d, 64);
    }
    float mean = s * (1.f / HIDDEN);
    float var  = sq * (1.f / HIDDEN) - mean * mean;
    float rstd = rsqrtf(var + 1e-5f);
    #pragma unroll
    for (int i = 0; i < 2; ++i)
        #pragma unroll
        for (int j = 0; j < 4; ++j) {
            int col = lane*4 + i*256 + j;
            float o = (v[i*4+j] - mean) * rstd * g[col] + bb[col];
            of[(size_t)row * HIDDEN + col] = o;
            if (WB) ob[(size_t)row * HIDDEN + col] = __float2bfloat16(o);
        }
}

// ---------------------------------------------------------------- launcher
extern "C" void kernel_launch(void* const* d_in, const int* in_sizes, int n_in,
                              void* d_out, int out_size, void* d_ws, size_t ws_size,
                              hipStream_t stream) {
    const float* x     = (const float*)d_in[0];
    const float* w_qkv = (const float*)d_in[1];
    const float* b_qkv = (const float*)d_in[2];
    const float* w_out = (const float*)d_in[3];
    const float* b_out = (const float*)d_in[4];
    const float* ln1_g = (const float*)d_in[5];
    const float* ln1_b = (const float*)d_in[6];
    const float* ln2_g = (const float*)d_in[7];
    const float* ln2_b = (const float*)d_in[8];
    const float* w1    = (const float*)d_in[9];
    const float* b1    = (const float*)d_in[10];
    const float* w2    = (const float*)d_in[11];
    const float* b2    = (const float*)d_in[12];
    const float* rel   = (const float*)d_in[13];
    float* out = (float*)d_out;

    char* ws = (char*)d_ws;
    bf16*  xb     = (bf16*)(ws + 0);
    bf16*  wqkv_t = (bf16*)(ws + 8388608);
    bf16*  wout_t = (bf16*)(ws + 9961472);
    bf16*  w1_t   = (bf16*)(ws + 10485760);
    bf16*  w2_t   = (bf16*)(ws + 12582912);
    bf16*  qkv    = (bf16*)(ws + 14680064);
    bf16*  v_t    = (bf16*)(ws + 39845888);
    bf16*  attn_o = (bf16*)(ws + 48234496);
    float* proj   = (float*)(ws + 56623104);
    float* x1     = (float*)(ws + 73400320);
    bf16*  h      = (bf16*)(ws + 14680064);   // reuses qkv+v_t (dead after attention)
    bf16*  x1b    = (bf16*)(ws + 90177536);

    // 1. casts / weight transposes
    cast_kernel<<<MM*HIDDEN/4/256, 256, 0, stream>>>(x, xb);
    wtrans_kernel<<<dim3(1536/32, 512/32),  256, 0, stream>>>(w_qkv, wqkv_t, 512, 1536);
    wtrans_kernel<<<dim3(512/32,  512/32),  256, 0, stream>>>(w_out, wout_t, 512, 512);
    wtrans_kernel<<<dim3(2048/32, 512/32),  256, 0, stream>>>(w1,    w1_t,   512, 2048);
    wtrans_kernel<<<dim3(512/32,  2048/32), 256, 0, stream>>>(w2,    w2_t,   2048, 512);
    // 2. qkv projection (V blocks write v_t directly)
    gemm_kernel<0,128,1,0><<<dim3(MM/128, 1536/128), 256, 0, stream>>>(
        xb, wqkv_t, b_qkv, nullptr, qkv, v_t, MM, 1536, 512);
    // 3. flash attention (128 q-rows per block, 8 waves x 16q)
    attn_kernel<<<dim3(TT/128, BB*HEADS), 512, 0, stream>>>(qkv, v_t, rel, attn_o);
    // 4. output projection + residual(x) -> f32
    gemm_kernel<1,64,0,1><<<dim3(MM/128, 512/64), 256, 0, stream>>>(
        attn_o, wout_t, b_out, x, proj, nullptr, MM, 512, 512);
    // 5. LN1
    ln_kernel<1><<<MM/4, 256, 0, stream>>>(proj, ln1_g, ln1_b, x1, x1b);
    // 6. MLP up + GELU(tanh)
    gemm_kernel<2,128,0,0><<<dim3(MM/128, 2048/128), 256, 0, stream>>>(
        x1b, w1_t, b1, nullptr, h, nullptr, MM, 2048, 512);
    // 7. MLP down + residual(x1) -> f32
    gemm_kernel<1,64,0,1><<<dim3(MM/128, 512/64), 256, 0, stream>>>(
        h, w2_t, b2, x1, proj, nullptr, MM, 512, 2048);
    // 8. LN2 -> output
    ln_kernel<0><<<MM/4, 256, 0, stream>>>(proj, ln2_g, ln2_b, out, nullptr);
}